// Round 6
// baseline (183.489 us; speedup 1.0000x reference)
//
#include <hip/hip_runtime.h>
#include <hip/hip_cooperative_groups.h>

namespace cg = cooperative_groups;

#define NGAUSS 2048
#define NPIX   65536
#define WID    512.0f
#define HEI    512.0f

// ---------------- tiled path geometry ----------------
#define NTX     8            // tiles in x (64 px each)
#define NTY     8
#define NTILE   (NTX * NTY)  // 64 tiles
#define TSHIFT  6
#define TPB     256

#define PREP_NB (NGAUSS / TPB)     // 8 prep block-units
#define GSEG    TPB                // 256: bulletproof cap per (prep-block,tile)
#define GT      (PREP_NB * GSEG)   // 2048 u32 per tile (gaussian list stride)

#define BIN_NB  32                 // 32 bin block-units
#define BIN_PPB (NPIX / BIN_NB)    // 2048 pixels per bin block
#define BIN_PPT (BIN_PPB / TPB)    // 8 per thread
#define PSEG    BIN_PPB            // 2048: bulletproof cap per (bin-block,tile)
#define PT      (BIN_NB * PSEG)    // 65536 u32 per tile (pixel list stride)

#define NCHUNK  8                  // pixel chunks per tile (covers 2048 px)
#define SPLAT_NB (NTILE * NCHUNK)  // 512 blocks

// sqrt of exp2-domain cutoff: w < 2^-27 dropped; error <= 2048*2^-27 = 1.5e-5
#define SQRT_CUT 5.2f

// workspace layout (bytes). Segment counts are WRITTEN (not accumulated) by
// exactly one block each, zeros included -> poison always overwritten ->
// NO memset and NO global atomics anywhere in the tiled path.
#define WS_PRM_OFF   0                               // 2048*48 = 98304
#define WS_GSEG_OFF  98304                           // 64*8 u32 = 2048
#define WS_PSEG_OFF  (WS_GSEG_OFF + NTILE*PREP_NB*4) // 64*32 u32 = 8192
#define WS_GLIST_OFF (WS_PSEG_OFF + NTILE*BIN_NB*4)  // 64*2048 u32 = 524288
#define WS_PLIST_OFF (WS_GLIST_OFF + NTILE*GT*4)     // 64*65536 u32 = 16 MiB
#define WS_NEED      (WS_PLIST_OFF + NTILE*PT*4)     // 17,410,048 B

// Per-gaussian packed params (3 x float4 = 48 B):
// p0 = (A, B, C, D) ; p1 = (E0, E1, r, g) ; p2 = (b, 0, 0, 0)
// dx = A*X + B*Y + E0 ; dy = C*X + D*Y + E1 ; w = exp2(-(dx^2+dy^2))
// A..E pre-scaled by K = sqrt(log2(e)) so exp(-q) == exp2(-q_scaled).

// ---- phase A1: pixel -> tile lists, block-private segments, one pass ----
__device__ __forceinline__ void do_bin(
    int bb, const float2* __restrict__ x,
    unsigned* __restrict__ pseg_cnt, unsigned* __restrict__ plist,
    unsigned* lcnt /* LDS[NTILE] */)
{
    const int tid = threadIdx.x;
    if (tid < NTILE) lcnt[tid] = 0u;
    __syncthreads();

    const int start = bb * BIN_PPB;
    #pragma unroll
    for (int k = 0; k < BIN_PPT; ++k) {
        int b = start + k * TPB + tid;
        float2 p = x[b];
        int tx = min(NTX - 1, max(0, ((int)p.x) >> TSHIFT));
        int ty = min(NTY - 1, max(0, ((int)p.y) >> TSHIFT));
        unsigned t = (unsigned)(ty * NTX + tx);
        unsigned slot = atomicAdd(&lcnt[t], 1u);   // LDS atomic; slot < 2048 always
        plist[t * PT + bb * PSEG + slot] = (unsigned)b;
    }
    __syncthreads();
    if (tid < NTILE) pseg_cnt[tid * BIN_NB + bb] = lcnt[tid];  // zeros too
}

// ---- phase A2: gaussian prep + bbox -> tile lists, block-private segments ----
__device__ __forceinline__ void do_prep(
    int pb, const float* __restrict__ rgb, const float* __restrict__ mu,
    const float* __restrict__ scale, const float* __restrict__ angle,
    float4* __restrict__ prm, unsigned* __restrict__ gseg_cnt,
    unsigned* __restrict__ glist, unsigned* lcnt /* LDS[NTILE] */)
{
    const int tid = threadIdx.x;
    if (tid < NTILE) lcnt[tid] = 0u;

    const int n = pb * TPB + tid;

    const float MU_BORDER = 1.05f;
    const float S_MIN = 1.0f / 30.0f;
    const float S_MAX = 1.0f / 0.75f;
    const float PI_APPROX = 3.1416f;
    const float K = 1.2011224087864498f;  // sqrt(log2(e))

    float mx = tanhf(mu[2*n+0]) * MU_BORDER * (0.5f * WID);
    float my = tanhf(mu[2*n+1]) * MU_BORDER * (0.5f * HEI);
    float al = tanhf(angle[n]) * PI_APPROX;
    float c = cosf(al);
    float s = sinf(al);
    float S0 = 1.0f / (1.0f + expf(-scale[2*n+0])) * (S_MAX - S_MIN) + S_MIN;
    float S1 = 1.0f / (1.0f + expf(-scale[2*n+1])) * (S_MAX - S_MIN) + S_MIN;

    float A  =  S0 * c * K;
    float Bc = -(S0 * s * K);
    float C  =  S1 * s * K;
    float D  =  S1 * c * K;
    float E0 = -(A * mx + Bc * my);
    float E1 = -(C * mx + D  * my);

    float r = 1.0f / (1.0f + expf(-rgb[3*n+0]));
    float g = 1.0f / (1.0f + expf(-rgb[3*n+1]));
    float b = 1.0f / (1.0f + expf(-rgb[3*n+2]));

    prm[3*n + 0] = make_float4(A, Bc, C, D);
    prm[3*n + 1] = make_float4(E0, E1, r, g);
    prm[3*n + 2] = make_float4(b, 0.f, 0.f, 0.f);

    // conservative bbox of {q_scaled <= SQRT_CUT^2}: ellipse projections
    float i0 = 1.0f / S0, i1 = 1.0f / S1;
    float hx = (SQRT_CUT / K) * sqrtf(c*c*i0*i0 + s*s*i1*i1);
    float hy = (SQRT_CUT / K) * sqrtf(s*s*i0*i0 + c*c*i1*i1);
    float px = mx + 0.5f * WID;
    float py = my + 0.5f * HEI;

    int ix0 = (int)floorf(px - hx), ix1 = (int)floorf(px + hx);
    int iy0 = (int)floorf(py - hy), iy1 = (int)floorf(py + hy);
    int tx0 = max(0, ix0 >> TSHIFT), tx1 = min(NTX - 1, ix1 >> TSHIFT);
    int ty0 = max(0, iy0 >> TSHIFT), ty1 = min(NTY - 1, iy1 >> TSHIFT);

    __syncthreads();   // lcnt zeroing visible
    for (int ty = ty0; ty <= ty1; ++ty)
        for (int tx = tx0; tx <= tx1; ++tx) {
            int t = ty * NTX + tx;
            unsigned slot = atomicAdd(&lcnt[t], 1u);   // slot < 256 always
            glist[t * GT + pb * GSEG + slot] = (unsigned)n;
        }
    __syncthreads();
    if (tid < NTILE) gseg_cnt[tid * PREP_NB + pb] = lcnt[tid];  // zeros too
}

// ---- phase B: per-(tile,chunk) splat; one thread = one pixel; plain stores ----
__device__ __forceinline__ void do_splat(
    int t, int chunk, const float2* __restrict__ x,
    const float4* __restrict__ prm,
    const unsigned* __restrict__ gseg_cnt, const unsigned* __restrict__ pseg_cnt,
    const unsigned* __restrict__ glist, const unsigned* __restrict__ plist,
    float* __restrict__ out,
    float4* sg /* LDS[TPB*3] */, unsigned* prefP /* LDS[33] */,
    unsigned* prefG /* LDS[9] */)
{
    const int tid = threadIdx.x;

    if (tid == 0) {
        unsigned acc = 0;
        prefP[0] = 0;
        #pragma unroll
        for (int i = 0; i < BIN_NB; ++i) { acc += pseg_cnt[t * BIN_NB + i]; prefP[i+1] = acc; }
        acc = 0;
        prefG[0] = 0;
        #pragma unroll
        for (int i = 0; i < PREP_NB; ++i) { acc += gseg_cnt[t * PREP_NB + i]; prefG[i+1] = acc; }
    }
    __syncthreads();

    const unsigned pcnt = min(prefP[BIN_NB], (unsigned)(NCHUNK * TPB));
    const unsigned gidx = (unsigned)(chunk * TPB + tid);
    if ((unsigned)(chunk * TPB) >= pcnt) return;   // uniform block exit

    const bool valid = gidx < pcnt;
    unsigned gq = valid ? gidx : 0u;
    // branchless binary search: last s with prefP[s] <= gq  (s in [0,32))
    int s = 0;
    #pragma unroll
    for (int step = 16; step >= 1; step >>= 1)
        if (prefP[s + step] <= gq) s += step;
    unsigned pid = plist[t * PT + s * PSEG + (gq - prefP[s])];

    float2 p = x[pid];
    float X = p.x - 0.5f * WID;
    float Y = p.y - 0.5f * HEI;

    const unsigned gcnt = prefG[PREP_NB];
    float ar = 0.f, ag = 0.f, ab = 0.f;

    for (unsigned g0 = 0; g0 < gcnt; g0 += TPB) {
        __syncthreads();
        unsigned gi = g0 + tid;
        if (gi < gcnt) {
            int gs = 0;
            #pragma unroll
            for (int step = 4; step >= 1; step >>= 1)
                if (prefG[gs + step] <= gi) gs += step;
            unsigned n = glist[t * GT + gs * GSEG + (gi - prefG[gs])];
            sg[3*tid + 0] = prm[3*n + 0];
            sg[3*tid + 1] = prm[3*n + 1];
            sg[3*tid + 2] = prm[3*n + 2];
        }
        __syncthreads();

        unsigned cnt = min((unsigned)TPB, gcnt - g0);
        #pragma unroll 4
        for (unsigned j = 0; j < cnt; ++j) {
            float4 c0 = sg[3*j + 0];
            float4 c1 = sg[3*j + 1];
            float4 c2 = sg[3*j + 2];
            float dx = fmaf(c0.x, X, fmaf(c0.y, Y, c1.x));
            float dy = fmaf(c0.z, X, fmaf(c0.w, Y, c1.y));
            float q  = fmaf(dx, dx, dy * dy);
            float w  = __builtin_amdgcn_exp2f(-q);
            ar = fmaf(w, c1.z, ar);
            ag = fmaf(w, c1.w, ag);
            ab = fmaf(w, c2.x, ab);
        }
    }

    if (valid) {                 // exactly one writer per pixel; no pre-zero needed
        out[3*pid + 0] = ar;
        out[3*pid + 1] = ag;
        out[3*pid + 2] = ab;
    }
}

// ---- fused cooperative kernel: setup -> grid.sync -> splat (1 dispatch) ----
__global__ __launch_bounds__(256) void fused_kernel(
    const float2* __restrict__ x, const float* __restrict__ rgb,
    const float* __restrict__ mu, const float* __restrict__ scale,
    const float* __restrict__ angle, float4* __restrict__ prm,
    unsigned* __restrict__ gseg_cnt, unsigned* __restrict__ pseg_cnt,
    unsigned* __restrict__ glist, unsigned* __restrict__ plist,
    float* __restrict__ out)
{
    __shared__ unsigned lcnt[NTILE];
    __shared__ float4   sg[TPB * 3];
    __shared__ unsigned prefP[BIN_NB + 1];
    __shared__ unsigned prefG[PREP_NB + 1];

    const int bid = blockIdx.x;
    if (bid < BIN_NB) {
        do_bin(bid, x, pseg_cnt, plist, lcnt);
    } else if (bid < BIN_NB + PREP_NB) {
        do_prep(bid - BIN_NB, rgb, mu, scale, angle, prm, gseg_cnt, glist, lcnt);
    }
    __threadfence();               // device-scope release (cross-XCD visibility)
    cg::this_grid().sync();

    do_splat(bid >> 3, bid & (NCHUNK - 1), x, prm, gseg_cnt, pseg_cnt,
             glist, plist, out, sg, prefP, prefG);
}

// ---- non-cooperative fallback: same device code as 2 dispatches ----
__global__ __launch_bounds__(256) void setup_kernel(
    const float2* __restrict__ x, const float* __restrict__ rgb,
    const float* __restrict__ mu, const float* __restrict__ scale,
    const float* __restrict__ angle, float4* __restrict__ prm,
    unsigned* __restrict__ gseg_cnt, unsigned* __restrict__ pseg_cnt,
    unsigned* __restrict__ glist, unsigned* __restrict__ plist)
{
    __shared__ unsigned lcnt[NTILE];
    if (blockIdx.x < BIN_NB)
        do_bin(blockIdx.x, x, pseg_cnt, plist, lcnt);
    else
        do_prep(blockIdx.x - BIN_NB, rgb, mu, scale, angle, prm, gseg_cnt, glist, lcnt);
}

__global__ __launch_bounds__(256) void splat_kernel(
    const float2* __restrict__ x, const float4* __restrict__ prm,
    const unsigned* __restrict__ gseg_cnt, const unsigned* __restrict__ pseg_cnt,
    const unsigned* __restrict__ glist, const unsigned* __restrict__ plist,
    float* __restrict__ out)
{
    __shared__ float4   sg[TPB * 3];
    __shared__ unsigned prefP[BIN_NB + 1];
    __shared__ unsigned prefG[PREP_NB + 1];
    do_splat(blockIdx.x, blockIdx.y, x, prm, gseg_cnt, pseg_cnt,
             glist, plist, out, sg, prefP, prefG);
}

// ---------------- last-resort fallback: flat kernel (ws too small) ----------------
#define NSLICE 16
#define GPB    (NGAUSS / NSLICE)
#define PPB    512

__global__ __launch_bounds__(256) void splat_flat(
    const float2* __restrict__ x, const float* __restrict__ rgb,
    const float* __restrict__ mu, const float* __restrict__ scale,
    const float* __restrict__ angle, float* __restrict__ out)
{
    __shared__ float4 sh4[GPB * 2];
    __shared__ float  shb[GPB];

    const int slice = blockIdx.x & (NSLICE - 1);
    const int pg    = blockIdx.x >> 4;
    const int tid   = threadIdx.x;

    if (tid < GPB) {
        const float MU_BORDER = 1.05f;
        const float S_MIN = 1.0f / 30.0f;
        const float S_MAX = 1.0f / 0.75f;
        const float PI_APPROX = 3.1416f;
        const float K = 1.2011224087864498f;

        int n = slice * GPB + tid;
        float mx = tanhf(mu[2*n+0]) * MU_BORDER * (0.5f * WID);
        float my = tanhf(mu[2*n+1]) * MU_BORDER * (0.5f * HEI);
        float al = tanhf(angle[n]) * PI_APPROX;
        float c = cosf(al);
        float s = sinf(al);
        float S0 = 1.0f / (1.0f + expf(-scale[2*n+0])) * (S_MAX - S_MIN) + S_MIN;
        float S1 = 1.0f / (1.0f + expf(-scale[2*n+1])) * (S_MAX - S_MIN) + S_MIN;
        float A  =  S0 * c * K;
        float Bc = -(S0 * s * K);
        float C  =  S1 * s * K;
        float D  =  S1 * c * K;
        sh4[2*tid + 0] = make_float4(A, Bc, C, D);
        sh4[2*tid + 1] = make_float4(-(A * mx + Bc * my), -(C * mx + D * my),
                                     1.0f / (1.0f + expf(-rgb[3*n+0])),
                                     1.0f / (1.0f + expf(-rgb[3*n+1])));
        shb[tid] = 1.0f / (1.0f + expf(-rgb[3*n+2]));
    }
    __syncthreads();

    const int t0 = pg * PPB + tid;
    const int t1 = t0 + TPB;
    float2 xy0 = x[t0];
    float2 xy1 = x[t1];
    float X0 = xy0.x - 0.5f * WID, Y0 = xy0.y - 0.5f * HEI;
    float X1 = xy1.x - 0.5f * WID, Y1 = xy1.y - 0.5f * HEI;

    float ar0 = 0.f, ag0 = 0.f, ab0 = 0.f;
    float ar1 = 0.f, ag1 = 0.f, ab1 = 0.f;
    #pragma unroll 4
    for (int j = 0; j < GPB; ++j) {
        float4 c0 = sh4[2*j + 0];
        float4 c1 = sh4[2*j + 1];
        float bb  = shb[j];
        float dx0 = fmaf(c0.x, X0, fmaf(c0.y, Y0, c1.x));
        float dy0 = fmaf(c0.z, X0, fmaf(c0.w, Y0, c1.y));
        float w0  = __builtin_amdgcn_exp2f(-fmaf(dx0, dx0, dy0 * dy0));
        float dx1 = fmaf(c0.x, X1, fmaf(c0.y, Y1, c1.x));
        float dy1 = fmaf(c0.z, X1, fmaf(c0.w, Y1, c1.y));
        float w1  = __builtin_amdgcn_exp2f(-fmaf(dx1, dx1, dy1 * dy1));
        ar0 = fmaf(w0, c1.z, ar0); ag0 = fmaf(w0, c1.w, ag0); ab0 = fmaf(w0, bb, ab0);
        ar1 = fmaf(w1, c1.z, ar1); ag1 = fmaf(w1, c1.w, ag1); ab1 = fmaf(w1, bb, ab1);
    }

    atomicAdd(&out[3*t0 + 0], ar0);
    atomicAdd(&out[3*t0 + 1], ag0);
    atomicAdd(&out[3*t0 + 2], ab0);
    atomicAdd(&out[3*t1 + 0], ar1);
    atomicAdd(&out[3*t1 + 1], ag1);
    atomicAdd(&out[3*t1 + 2], ab1);
}

extern "C" void kernel_launch(void* const* d_in, const int* in_sizes, int n_in,
                              void* d_out, int out_size, void* d_ws, size_t ws_size,
                              hipStream_t stream) {
    const float* xf    = (const float*)d_in[0];  // [B,2]
    const float* rgb   = (const float*)d_in[1];  // [N,3]
    const float* mu    = (const float*)d_in[2];  // [N,2]
    const float* scale = (const float*)d_in[3];  // [N,2]
    const float* angle = (const float*)d_in[4];  // [N]

    if (ws_size >= (size_t)WS_NEED && d_ws != nullptr) {
        char* ws = (char*)d_ws;
        const float2* x2     = (const float2*)xf;
        float4*   prm        = (float4*)(ws + WS_PRM_OFF);
        unsigned* gseg_cnt   = (unsigned*)(ws + WS_GSEG_OFF);
        unsigned* pseg_cnt   = (unsigned*)(ws + WS_PSEG_OFF);
        unsigned* glist      = (unsigned*)(ws + WS_GLIST_OFF);
        unsigned* plist      = (unsigned*)(ws + WS_PLIST_OFF);
        float*    outp       = (float*)d_out;

        // no memsets: segment counts are plain-written (zeros included) and
        // every output pixel is plain-stored exactly once.
        void* args[] = { (void*)&x2, (void*)&rgb, (void*)&mu, (void*)&scale,
                         (void*)&angle, (void*)&prm, (void*)&gseg_cnt,
                         (void*)&pseg_cnt, (void*)&glist, (void*)&plist,
                         (void*)&outp };
        hipError_t e = hipLaunchCooperativeKernel(
            (const void*)fused_kernel, dim3(SPLAT_NB), dim3(TPB), args, 0, stream);
        if (e != hipSuccess) {
            // non-cooperative fallback: same device code, 2 dispatches
            hipLaunchKernelGGL(setup_kernel, dim3(BIN_NB + PREP_NB), dim3(TPB), 0,
                               stream, x2, rgb, mu, scale, angle,
                               prm, gseg_cnt, pseg_cnt, glist, plist);
            hipLaunchKernelGGL(splat_kernel, dim3(NTILE, NCHUNK), dim3(TPB), 0,
                               stream, x2, prm, gseg_cnt, pseg_cnt, glist, plist,
                               outp);
        }
    } else {
        // harness poisons d_out with 0xAA — flat fallback accumulates, so zero it
        hipMemsetAsync(d_out, 0, (size_t)out_size * sizeof(float), stream);
        hipLaunchKernelGGL(splat_flat, dim3(NPIX / PPB * NSLICE), dim3(TPB), 0,
                           stream, (const float2*)xf, rgb, mu, scale, angle,
                           (float*)d_out);
    }
}

// Round 7
// 74.023 us; speedup vs baseline: 2.4788x; 2.4788x over previous
//
#include <hip/hip_runtime.h>

#define NGAUSS 2048
#define NPIX   65536
#define WID    512.0f
#define HEI    512.0f

// ---------------- tiled path geometry ----------------
#define NTX     8            // tiles in x (64 px each)
#define NTY     8
#define NTILE   (NTX * NTY)  // 64 tiles
#define TSHIFT  6
#define TPB     256

#define PREP_NB (NGAUSS / TPB)     // 8 prep block-units
#define GSEG    TPB                // 256: bulletproof cap per (prep-block,tile)
#define GT      (PREP_NB * GSEG)   // 2048 u32 per tile (gaussian list stride)

#define BIN_NB  32                 // 32 bin block-units
#define BIN_PPB (NPIX / BIN_NB)    // 2048 pixels per bin block
#define BIN_PPT (BIN_PPB / TPB)    // 8 per thread
#define PSEG    BIN_PPB            // 2048: bulletproof cap per (bin-block,tile)
#define PT      (BIN_NB * PSEG)    // 65536 u32 per tile (pixel list stride)

#define NCHUNK  8                  // pixel chunks per tile (covers 2048 px)

// sqrt of exp2-domain cutoff: w < 2^-27 dropped; error <= 2048*2^-27 = 1.5e-5
#define SQRT_CUT 5.2f

// workspace layout (bytes). Segment counts are WRITTEN (not accumulated) by
// exactly one block each, zeros included -> poison always overwritten ->
// NO memset and NO global atomics anywhere in the tiled path.
// NOTE (round 6 lesson): cg::this_grid().sync() cost ~100us on MI355X
// (VALUBusy 1%) — a kernel boundary IS the cheap grid barrier. 2 dispatches.
#define WS_PRM_OFF   0                               // 2048*48 = 98304
#define WS_GSEG_OFF  98304                           // 64*8 u32 = 2048
#define WS_PSEG_OFF  (WS_GSEG_OFF + NTILE*PREP_NB*4) // 64*32 u32 = 8192
#define WS_GLIST_OFF (WS_PSEG_OFF + NTILE*BIN_NB*4)  // 64*2048 u32 = 524288
#define WS_PLIST_OFF (WS_GLIST_OFF + NTILE*GT*4)     // 64*65536 u32 = 16 MiB
#define WS_NEED      (WS_PLIST_OFF + NTILE*PT*4)     // 17,410,048 B

// Per-gaussian packed params (3 x float4 = 48 B):
// p0 = (A, B, C, D) ; p1 = (E0, E1, r, g) ; p2 = (b, 0, 0, 0)
// dx = A*X + B*Y + E0 ; dy = C*X + D*Y + E1 ; w = exp2(-(dx^2+dy^2))
// A..E pre-scaled by K = sqrt(log2(e)) so exp(-q) == exp2(-q_scaled).

// ---- phase A1: pixel -> tile lists, block-private segments, one pass ----
__device__ __forceinline__ void do_bin(
    int bb, const float2* __restrict__ x,
    unsigned* __restrict__ pseg_cnt, unsigned* __restrict__ plist,
    unsigned* lcnt /* LDS[NTILE] */)
{
    const int tid = threadIdx.x;
    if (tid < NTILE) lcnt[tid] = 0u;
    __syncthreads();

    const int start = bb * BIN_PPB;
    #pragma unroll
    for (int k = 0; k < BIN_PPT; ++k) {
        int b = start + k * TPB + tid;
        float2 p = x[b];
        int tx = min(NTX - 1, max(0, ((int)p.x) >> TSHIFT));
        int ty = min(NTY - 1, max(0, ((int)p.y) >> TSHIFT));
        unsigned t = (unsigned)(ty * NTX + tx);
        unsigned slot = atomicAdd(&lcnt[t], 1u);   // LDS atomic; slot < 2048 always
        plist[t * PT + bb * PSEG + slot] = (unsigned)b;
    }
    __syncthreads();
    if (tid < NTILE) pseg_cnt[tid * BIN_NB + bb] = lcnt[tid];  // zeros too
}

// ---- phase A2: gaussian prep + bbox -> tile lists, block-private segments ----
__device__ __forceinline__ void do_prep(
    int pb, const float* __restrict__ rgb, const float* __restrict__ mu,
    const float* __restrict__ scale, const float* __restrict__ angle,
    float4* __restrict__ prm, unsigned* __restrict__ gseg_cnt,
    unsigned* __restrict__ glist, unsigned* lcnt /* LDS[NTILE] */)
{
    const int tid = threadIdx.x;
    if (tid < NTILE) lcnt[tid] = 0u;

    const int n = pb * TPB + tid;

    const float MU_BORDER = 1.05f;
    const float S_MIN = 1.0f / 30.0f;
    const float S_MAX = 1.0f / 0.75f;
    const float PI_APPROX = 3.1416f;
    const float K = 1.2011224087864498f;  // sqrt(log2(e))

    float mx = tanhf(mu[2*n+0]) * MU_BORDER * (0.5f * WID);
    float my = tanhf(mu[2*n+1]) * MU_BORDER * (0.5f * HEI);
    float al = tanhf(angle[n]) * PI_APPROX;
    float c = cosf(al);
    float s = sinf(al);
    float S0 = 1.0f / (1.0f + expf(-scale[2*n+0])) * (S_MAX - S_MIN) + S_MIN;
    float S1 = 1.0f / (1.0f + expf(-scale[2*n+1])) * (S_MAX - S_MIN) + S_MIN;

    float A  =  S0 * c * K;
    float Bc = -(S0 * s * K);
    float C  =  S1 * s * K;
    float D  =  S1 * c * K;
    float E0 = -(A * mx + Bc * my);
    float E1 = -(C * mx + D  * my);

    float r = 1.0f / (1.0f + expf(-rgb[3*n+0]));
    float g = 1.0f / (1.0f + expf(-rgb[3*n+1]));
    float b = 1.0f / (1.0f + expf(-rgb[3*n+2]));

    prm[3*n + 0] = make_float4(A, Bc, C, D);
    prm[3*n + 1] = make_float4(E0, E1, r, g);
    prm[3*n + 2] = make_float4(b, 0.f, 0.f, 0.f);

    // conservative bbox of {q_scaled <= SQRT_CUT^2}: ellipse projections
    float i0 = 1.0f / S0, i1 = 1.0f / S1;
    float hx = (SQRT_CUT / K) * sqrtf(c*c*i0*i0 + s*s*i1*i1);
    float hy = (SQRT_CUT / K) * sqrtf(s*s*i0*i0 + c*c*i1*i1);
    float px = mx + 0.5f * WID;
    float py = my + 0.5f * HEI;

    int ix0 = (int)floorf(px - hx), ix1 = (int)floorf(px + hx);
    int iy0 = (int)floorf(py - hy), iy1 = (int)floorf(py + hy);
    int tx0 = max(0, ix0 >> TSHIFT), tx1 = min(NTX - 1, ix1 >> TSHIFT);
    int ty0 = max(0, iy0 >> TSHIFT), ty1 = min(NTY - 1, iy1 >> TSHIFT);

    __syncthreads();   // lcnt zeroing visible
    for (int ty = ty0; ty <= ty1; ++ty)
        for (int tx = tx0; tx <= tx1; ++tx) {
            int t = ty * NTX + tx;
            unsigned slot = atomicAdd(&lcnt[t], 1u);   // slot < 256 always
            glist[t * GT + pb * GSEG + slot] = (unsigned)n;
        }
    __syncthreads();
    if (tid < NTILE) gseg_cnt[tid * PREP_NB + pb] = lcnt[tid];  // zeros too
}

// ---- kernel 1: fused setup (bin blocks 0..31, prep blocks 32..39) ----
__global__ __launch_bounds__(256) void setup_kernel(
    const float2* __restrict__ x, const float* __restrict__ rgb,
    const float* __restrict__ mu, const float* __restrict__ scale,
    const float* __restrict__ angle, float4* __restrict__ prm,
    unsigned* __restrict__ gseg_cnt, unsigned* __restrict__ pseg_cnt,
    unsigned* __restrict__ glist, unsigned* __restrict__ plist)
{
    __shared__ unsigned lcnt[NTILE];
    if (blockIdx.x < BIN_NB)
        do_bin(blockIdx.x, x, pseg_cnt, plist, lcnt);
    else
        do_prep(blockIdx.x - BIN_NB, rgb, mu, scale, angle, prm, gseg_cnt, glist, lcnt);
}

// ---- kernel 2: per-(tile,chunk) splat; one thread = one pixel; plain stores ----
__global__ __launch_bounds__(256) void splat_kernel(
    const float2* __restrict__ x, const float4* __restrict__ prm,
    const unsigned* __restrict__ gseg_cnt, const unsigned* __restrict__ pseg_cnt,
    const unsigned* __restrict__ glist, const unsigned* __restrict__ plist,
    float* __restrict__ out)
{
    __shared__ float4   sg[TPB * 3];
    __shared__ unsigned prefP[BIN_NB + 1];
    __shared__ unsigned prefG[PREP_NB + 1];

    const int t     = blockIdx.x;
    const int chunk = blockIdx.y;
    const int tid   = threadIdx.x;

    if (tid == 0) {
        unsigned acc = 0;
        prefP[0] = 0;
        #pragma unroll
        for (int i = 0; i < BIN_NB; ++i) { acc += pseg_cnt[t * BIN_NB + i]; prefP[i+1] = acc; }
        acc = 0;
        prefG[0] = 0;
        #pragma unroll
        for (int i = 0; i < PREP_NB; ++i) { acc += gseg_cnt[t * PREP_NB + i]; prefG[i+1] = acc; }
    }
    __syncthreads();

    const unsigned pcnt = min(prefP[BIN_NB], (unsigned)(NCHUNK * TPB));
    const unsigned gidx = (unsigned)(chunk * TPB + tid);
    if ((unsigned)(chunk * TPB) >= pcnt) return;   // uniform block exit

    const bool valid = gidx < pcnt;
    unsigned gq = valid ? gidx : 0u;
    // branchless binary search: last s with prefP[s] <= gq  (s in [0,32))
    int s = 0;
    #pragma unroll
    for (int step = 16; step >= 1; step >>= 1)
        if (prefP[s + step] <= gq) s += step;
    unsigned pid = plist[t * PT + s * PSEG + (gq - prefP[s])];

    float2 p = x[pid];
    float X = p.x - 0.5f * WID;
    float Y = p.y - 0.5f * HEI;

    const unsigned gcnt = prefG[PREP_NB];
    float ar = 0.f, ag = 0.f, ab = 0.f;

    for (unsigned g0 = 0; g0 < gcnt; g0 += TPB) {
        __syncthreads();
        unsigned gi = g0 + tid;
        if (gi < gcnt) {
            int gs = 0;
            #pragma unroll
            for (int step = 4; step >= 1; step >>= 1)
                if (prefG[gs + step] <= gi) gs += step;
            unsigned n = glist[t * GT + gs * GSEG + (gi - prefG[gs])];
            sg[3*tid + 0] = prm[3*n + 0];
            sg[3*tid + 1] = prm[3*n + 1];
            sg[3*tid + 2] = prm[3*n + 2];
        }
        __syncthreads();

        unsigned cnt = min((unsigned)TPB, gcnt - g0);
        #pragma unroll 4
        for (unsigned j = 0; j < cnt; ++j) {
            float4 c0 = sg[3*j + 0];
            float4 c1 = sg[3*j + 1];
            float4 c2 = sg[3*j + 2];
            float dx = fmaf(c0.x, X, fmaf(c0.y, Y, c1.x));
            float dy = fmaf(c0.z, X, fmaf(c0.w, Y, c1.y));
            float q  = fmaf(dx, dx, dy * dy);
            float w  = __builtin_amdgcn_exp2f(-q);
            ar = fmaf(w, c1.z, ar);
            ag = fmaf(w, c1.w, ag);
            ab = fmaf(w, c2.x, ab);
        }
    }

    if (valid) {                 // exactly one writer per pixel; no pre-zero needed
        out[3*pid + 0] = ar;
        out[3*pid + 1] = ag;
        out[3*pid + 2] = ab;
    }
}

// ---------------- last-resort fallback: flat kernel (ws too small) ----------------
#define NSLICE 16
#define GPB    (NGAUSS / NSLICE)
#define PPB    512

__global__ __launch_bounds__(256) void splat_flat(
    const float2* __restrict__ x, const float* __restrict__ rgb,
    const float* __restrict__ mu, const float* __restrict__ scale,
    const float* __restrict__ angle, float* __restrict__ out)
{
    __shared__ float4 sh4[GPB * 2];
    __shared__ float  shb[GPB];

    const int slice = blockIdx.x & (NSLICE - 1);
    const int pg    = blockIdx.x >> 4;
    const int tid   = threadIdx.x;

    if (tid < GPB) {
        const float MU_BORDER = 1.05f;
        const float S_MIN = 1.0f / 30.0f;
        const float S_MAX = 1.0f / 0.75f;
        const float PI_APPROX = 3.1416f;
        const float K = 1.2011224087864498f;

        int n = slice * GPB + tid;
        float mx = tanhf(mu[2*n+0]) * MU_BORDER * (0.5f * WID);
        float my = tanhf(mu[2*n+1]) * MU_BORDER * (0.5f * HEI);
        float al = tanhf(angle[n]) * PI_APPROX;
        float c = cosf(al);
        float s = sinf(al);
        float S0 = 1.0f / (1.0f + expf(-scale[2*n+0])) * (S_MAX - S_MIN) + S_MIN;
        float S1 = 1.0f / (1.0f + expf(-scale[2*n+1])) * (S_MAX - S_MIN) + S_MIN;
        float A  =  S0 * c * K;
        float Bc = -(S0 * s * K);
        float C  =  S1 * s * K;
        float D  =  S1 * c * K;
        sh4[2*tid + 0] = make_float4(A, Bc, C, D);
        sh4[2*tid + 1] = make_float4(-(A * mx + Bc * my), -(C * mx + D * my),
                                     1.0f / (1.0f + expf(-rgb[3*n+0])),
                                     1.0f / (1.0f + expf(-rgb[3*n+1])));
        shb[tid] = 1.0f / (1.0f + expf(-rgb[3*n+2]));
    }
    __syncthreads();

    const int t0 = pg * PPB + tid;
    const int t1 = t0 + TPB;
    float2 xy0 = x[t0];
    float2 xy1 = x[t1];
    float X0 = xy0.x - 0.5f * WID, Y0 = xy0.y - 0.5f * HEI;
    float X1 = xy1.x - 0.5f * WID, Y1 = xy1.y - 0.5f * HEI;

    float ar0 = 0.f, ag0 = 0.f, ab0 = 0.f;
    float ar1 = 0.f, ag1 = 0.f, ab1 = 0.f;
    #pragma unroll 4
    for (int j = 0; j < GPB; ++j) {
        float4 c0 = sh4[2*j + 0];
        float4 c1 = sh4[2*j + 1];
        float bb  = shb[j];
        float dx0 = fmaf(c0.x, X0, fmaf(c0.y, Y0, c1.x));
        float dy0 = fmaf(c0.z, X0, fmaf(c0.w, Y0, c1.y));
        float w0  = __builtin_amdgcn_exp2f(-fmaf(dx0, dx0, dy0 * dy0));
        float dx1 = fmaf(c0.x, X1, fmaf(c0.y, Y1, c1.x));
        float dy1 = fmaf(c0.z, X1, fmaf(c0.w, Y1, c1.y));
        float w1  = __builtin_amdgcn_exp2f(-fmaf(dx1, dx1, dy1 * dy1));
        ar0 = fmaf(w0, c1.z, ar0); ag0 = fmaf(w0, c1.w, ag0); ab0 = fmaf(w0, bb, ab0);
        ar1 = fmaf(w1, c1.z, ar1); ag1 = fmaf(w1, c1.w, ag1); ab1 = fmaf(w1, bb, ab1);
    }

    atomicAdd(&out[3*t0 + 0], ar0);
    atomicAdd(&out[3*t0 + 1], ag0);
    atomicAdd(&out[3*t0 + 2], ab0);
    atomicAdd(&out[3*t1 + 0], ar1);
    atomicAdd(&out[3*t1 + 1], ag1);
    atomicAdd(&out[3*t1 + 2], ab1);
}

extern "C" void kernel_launch(void* const* d_in, const int* in_sizes, int n_in,
                              void* d_out, int out_size, void* d_ws, size_t ws_size,
                              hipStream_t stream) {
    const float* xf    = (const float*)d_in[0];  // [B,2]
    const float* rgb   = (const float*)d_in[1];  // [N,3]
    const float* mu    = (const float*)d_in[2];  // [N,2]
    const float* scale = (const float*)d_in[3];  // [N,2]
    const float* angle = (const float*)d_in[4];  // [N]

    if (ws_size >= (size_t)WS_NEED && d_ws != nullptr) {
        char* ws = (char*)d_ws;
        const float2* x2     = (const float2*)xf;
        float4*   prm        = (float4*)(ws + WS_PRM_OFF);
        unsigned* gseg_cnt   = (unsigned*)(ws + WS_GSEG_OFF);
        unsigned* pseg_cnt   = (unsigned*)(ws + WS_PSEG_OFF);
        unsigned* glist      = (unsigned*)(ws + WS_GLIST_OFF);
        unsigned* plist      = (unsigned*)(ws + WS_PLIST_OFF);

        // no memsets: segment counts are plain-written (zeros included) and
        // every output pixel is plain-stored exactly once. The kernel
        // boundary is the grid barrier (round-6 lesson: grid.sync ~100us).
        hipLaunchKernelGGL(setup_kernel, dim3(BIN_NB + PREP_NB), dim3(TPB), 0,
                           stream, x2, rgb, mu, scale, angle,
                           prm, gseg_cnt, pseg_cnt, glist, plist);
        hipLaunchKernelGGL(splat_kernel, dim3(NTILE, NCHUNK), dim3(TPB), 0,
                           stream, x2, prm, gseg_cnt, pseg_cnt, glist, plist,
                           (float*)d_out);
    } else {
        // harness poisons d_out with 0xAA — flat fallback accumulates, so zero it
        hipMemsetAsync(d_out, 0, (size_t)out_size * sizeof(float), stream);
        hipLaunchKernelGGL(splat_flat, dim3(NPIX / PPB * NSLICE), dim3(TPB), 0,
                           stream, (const float2*)xf, rgb, mu, scale, angle,
                           (float*)d_out);
    }
}